// Round 3
// baseline (186.206 us; speedup 1.0000x reference)
//
#include <hip/hip_runtime.h>
#include <hip/hip_cooperative_groups.h>

namespace cg = cooperative_groups;

#define BSEG   64
#define LATENT 256
#define NB     1024
#define ITERS  4                         // ceil(1M float4 / (1024*256))
#define SCALE_F   1.0995116e12f          // 2^40 (e <= 1 after local-max subtraction)
#define INV_SCALE 9.094947017729282e-13  // 2^-40 (double)
#define ENC_NEG_INF 0x007FFFFFu          // enc_f32(-INFINITY)

// Monotone order-preserving f32 -> u32 encoding (for native integer atomicMax).
__device__ __forceinline__ unsigned enc_f32(float x) {
    unsigned u = __float_as_uint(x);
    return (u & 0x80000000u) ? ~u : (u | 0x80000000u);
}
__device__ __forceinline__ float dec_f32(unsigned e) {
    unsigned u = (e & 0x80000000u) ? (e & 0x7FFFFFFFu) : ~e;
    return __uint_as_float(u);
}

// A: uncertainty[b] = 128*log(2*pi*e) + sum_k log(std)
__global__ __launch_bounds__(256) void k_unc(const float* __restrict__ pstd,
                                             float* __restrict__ unc,
                                             float* __restrict__ out_unc) {
    int b = blockIdx.x;
    float v = logf(pstd[b * LATENT + threadIdx.x]);
#pragma unroll
    for (int off = 32; off > 0; off >>= 1) v += __shfl_down(v, off, 64);
    __shared__ float part[4];
    int lane = threadIdx.x & 63, wv = threadIdx.x >> 6;
    if (lane == 0) part[wv] = v;
    __syncthreads();
    if (threadIdx.x == 0) {
        float s = part[0] + part[1] + part[2] + part[3];
        float u = 128.0f * 2.83787706640934548f + s;
        unc[b]     = u;
        out_unc[b] = u;
    }
}

// Fused cooperative kernel: priority + segment-softmax, data held in registers
// across two grid syncs.
__global__ __launch_bounds__(256, 4) void k_fused(
    const float* __restrict__ coh, const int* __restrict__ batch,
    const float* __restrict__ unc,
    float* __restrict__ bmax, float* __restrict__ bsum,
    float* __restrict__ maxf, float* __restrict__ rsum,
    float* __restrict__ pri, float* __restrict__ nrm, int n) {
    cg::grid_group grid = cg::this_grid();

    __shared__ float    unc_s[BSEG];
    __shared__ unsigned max_s[4][BSEG];
    __shared__ unsigned long long sum_s[4][BSEG];
    __shared__ float m_s[BSEG];
    __shared__ float r_s[BSEG];

    int t = threadIdx.x, wv = t >> 6;
    if (t < BSEG) {
        unc_s[t] = unc[t];
#pragma unroll
        for (int w = 0; w < 4; ++w) { max_s[w][t] = ENC_NEG_INF; sum_s[w][t] = 0ull; }
    }
    __syncthreads();

    int gid = blockIdx.x * 256 + t;
    int nv  = n >> 2;

    // ---- Phase 1: priority + per-block max ----
    float4 pr[ITERS];
    int4   bi[ITERS];
#pragma unroll
    for (int u = 0; u < ITERS; ++u) {
        int i = gid + u * (NB * 256);
        if (i < nv) {
            float4 cv = ((const float4*)coh)[i];
            int4   bv = ((const int4*)batch)[i];
            float4 pv;
            pv.x = cv.x * unc_s[bv.x];
            pv.y = cv.y * unc_s[bv.y];
            pv.z = cv.z * unc_s[bv.z];
            pv.w = cv.w * unc_s[bv.w];
            bi[u] = bv; pr[u] = pv;
            ((float4*)pri)[i] = pv;
            atomicMax(&max_s[wv][bv.x], enc_f32(pv.x));
            atomicMax(&max_s[wv][bv.y], enc_f32(pv.y));
            atomicMax(&max_s[wv][bv.z], enc_f32(pv.z));
            atomicMax(&max_s[wv][bv.w], enc_f32(pv.w));
        } else {
            bi[u].x = -1;
        }
    }
    // scalar tail (n % 4), handled by block 0
    float p_t = 0.0f; int b_t = -1;
    if (blockIdx.x == 0) {
        int rem = n - (nv << 2);
        if (t < rem) {
            int i = (nv << 2) + t;
            b_t = batch[i];
            p_t = coh[i] * unc_s[b_t];
            pri[i] = p_t;
            atomicMax(&max_s[wv][b_t], enc_f32(p_t));
        }
    }
    __syncthreads();
    if (t < BSEG) {
        unsigned m = max(max(max_s[0][t], max_s[1][t]), max(max_s[2][t], max_s[3][t]));
        float mf = dec_f32(m);
        m_s[t] = mf;
        bmax[blockIdx.x * BSEG + t] = mf;
    }
    __syncthreads();

    // ---- Phase 1b: partial sums exp(p - m_blk) in fixed-point u64 ----
#pragma unroll
    for (int u = 0; u < ITERS; ++u) {
        if (bi[u].x >= 0) {
            int4 bv = bi[u]; float4 pv = pr[u];
            atomicAdd(&sum_s[wv][bv.x], (unsigned long long)(expf(pv.x - m_s[bv.x]) * SCALE_F));
            atomicAdd(&sum_s[wv][bv.y], (unsigned long long)(expf(pv.y - m_s[bv.y]) * SCALE_F));
            atomicAdd(&sum_s[wv][bv.z], (unsigned long long)(expf(pv.z - m_s[bv.z]) * SCALE_F));
            atomicAdd(&sum_s[wv][bv.w], (unsigned long long)(expf(pv.w - m_s[bv.w]) * SCALE_F));
        }
    }
    if (b_t >= 0)
        atomicAdd(&sum_s[wv][b_t], (unsigned long long)(expf(p_t - m_s[b_t]) * SCALE_F));
    __syncthreads();
    if (t < BSEG) {
        unsigned long long tot = sum_s[0][t] + sum_s[1][t] + sum_s[2][t] + sum_s[3][t];
        bsum[blockIdx.x * BSEG + t] = (float)((double)tot * INV_SCALE);
    }

    grid.sync();

    // ---- Combine: blocks 0..63 each merge one segment's 1024 partials ----
    if (blockIdx.x < BSEG) {
        int s = blockIdx.x;
        float m = -INFINITY;
        for (int i = t; i < NB; i += 256) m = fmaxf(m, bmax[i * BSEG + s]);
#pragma unroll
        for (int off = 32; off > 0; off >>= 1) m = fmaxf(m, __shfl_down(m, off, 64));
        __shared__ float cpart[4];
        if ((t & 63) == 0) cpart[t >> 6] = m;
        __syncthreads();
        float m_g = fmaxf(fmaxf(cpart[0], cpart[1]), fmaxf(cpart[2], cpart[3]));
        float acc = 0.0f;
        for (int i = t; i < NB; i += 256) acc += bsum[i * BSEG + s] * expf(bmax[i * BSEG + s] - m_g);
#pragma unroll
        for (int off = 32; off > 0; off >>= 1) acc += __shfl_down(acc, off, 64);
        __shared__ float cpart2[4];
        if ((t & 63) == 0) cpart2[t >> 6] = acc;
        __syncthreads();
        if (t == 0) {
            float tot = cpart2[0] + cpart2[1] + cpart2[2] + cpart2[3];
            maxf[s] = m_g;
            rsum[s] = 1.0f / tot;
        }
    }

    grid.sync();

    // ---- Phase 2: normalized from registers ----
    if (t < BSEG) { m_s[t] = maxf[t]; r_s[t] = rsum[t]; }
    __syncthreads();
#pragma unroll
    for (int u = 0; u < ITERS; ++u) {
        int i = gid + u * (NB * 256);
        if (i < nv && bi[u].x >= 0) {
            int4 bv = bi[u]; float4 pv = pr[u];
            float4 ov;
            ov.x = expf(pv.x - m_s[bv.x]) * r_s[bv.x];
            ov.y = expf(pv.y - m_s[bv.y]) * r_s[bv.y];
            ov.z = expf(pv.z - m_s[bv.z]) * r_s[bv.z];
            ov.w = expf(pv.w - m_s[bv.w]) * r_s[bv.w];
            ((float4*)nrm)[i] = ov;
        }
    }
    if (b_t >= 0)
        nrm[(nv << 2) + t] = expf(p_t - m_s[b_t]) * r_s[b_t];
}

extern "C" void kernel_launch(void* const* d_in, const int* in_sizes, int n_in,
                              void* d_out, int out_size, void* d_ws, size_t ws_size,
                              hipStream_t stream) {
    const float* coh   = (const float*)d_in[0];
    // d_in[1] = posterior_mean (unused by the reference outputs)
    const float* pstd  = (const float*)d_in[2];
    const int*   batch = (const int*)d_in[3];
    int n = in_sizes[0];

    float* out     = (float*)d_out;
    float* out_pri = out;
    float* out_nrm = out + n;
    float* out_unc = out + 2 * (size_t)n;

    // ws layout (bytes):
    // [0,256)    unc
    // [256,512)  maxf
    // [512,768)  rsum
    // [1024, 1024+NB*64*4)             bmax (f32 per-block maxima)
    // [.., .. + NB*64*4)               bsum (f32 per-block sums)
    float* ws_unc  = (float*)d_ws;
    float* ws_maxf = (float*)((char*)d_ws + 256);
    float* ws_rsum = (float*)((char*)d_ws + 512);
    float* ws_bmax = (float*)((char*)d_ws + 1024);
    float* ws_bsum = (float*)((char*)d_ws + 1024 + NB * BSEG * 4);

    k_unc<<<BSEG, 256, 0, stream>>>(pstd, ws_unc, out_unc);

    void* args[] = {(void*)&coh, (void*)&batch, (void*)&ws_unc,
                    (void*)&ws_bmax, (void*)&ws_bsum,
                    (void*)&ws_maxf, (void*)&ws_rsum,
                    (void*)&out_pri, (void*)&out_nrm, (void*)&n};
    hipLaunchCooperativeKernel((const void*)k_fused, dim3(NB), dim3(256),
                               args, 0, stream);
}

// Round 4
// 32.859 us; speedup vs baseline: 5.6668x; 5.6668x over previous
//
#include <hip/hip_runtime.h>

#define BSEG   64
#define LATENT 256
#define NB     1024            // blocks for pass 1 (partials sized to this)
#define NB2    2048            // blocks for pass 2 (pure streaming)
#define ITERS  4               // 1M float4 / (NB*256)
#define SCALE_F   1.0995116e12f          // 2^40 (e <= 1 after block-max subtraction)
#define INV_SCALE 9.094947017729282e-13 // 2^-40 (double)
#define ENC_NEG_INF 0x007FFFFFu          // enc_f32(-INFINITY)

// Monotone order-preserving f32 -> u32 encoding (for native integer atomicMax).
__device__ __forceinline__ unsigned enc_f32(float x) {
    unsigned u = __float_as_uint(x);
    return (u & 0x80000000u) ? ~u : (u | 0x80000000u);
}
__device__ __forceinline__ float dec_f32(unsigned e) {
    unsigned u = (e & 0x80000000u) ? (e & 0x7FFFFFFFu) : ~e;
    return __uint_as_float(u);
}

// A: uncertainty[b] = 128*log(2*pi*e) + sum_k log(std)
__global__ __launch_bounds__(256) void k_unc(const float* __restrict__ pstd,
                                             float* __restrict__ unc,
                                             float* __restrict__ out_unc) {
    int b = blockIdx.x;
    float v = logf(pstd[b * LATENT + threadIdx.x]);
#pragma unroll
    for (int off = 32; off > 0; off >>= 1) v += __shfl_down(v, off, 64);
    __shared__ float part[4];
    int lane = threadIdx.x & 63, wv = threadIdx.x >> 6;
    if (lane == 0) part[wv] = v;
    __syncthreads();
    if (threadIdx.x == 0) {
        float s = part[0] + part[1] + part[2] + part[3];
        float u = 128.0f * 2.83787706640934548f + s;
        unc[b]     = u;
        out_unc[b] = u;
    }
}

// Pass 1: priority (+u8 batch sidecar) + per-block online softmax partials.
// Registers hold 16 (p, b) pairs across the two sub-phases; no grid sync.
__global__ __launch_bounds__(256, 4) void k_pass1(
    const float* __restrict__ coh, const int* __restrict__ batch,
    const float* __restrict__ unc,
    float* __restrict__ bmax_t,          // [BSEG][NB] transposed block maxima
    float* __restrict__ bsum_t,          // [BSEG][NB] transposed block sums
    unsigned char* __restrict__ b8,      // optional u8 batch sidecar
    float* __restrict__ pri, int n, int use8) {
    __shared__ float    unc_s[BSEG];
    __shared__ unsigned max_s[4][BSEG];
    __shared__ unsigned long long sum_s[4][BSEG];
    __shared__ float m_s[BSEG];

    int t = threadIdx.x, wv = t >> 6;
    if (t < BSEG) {
        unc_s[t] = unc[t];
#pragma unroll
        for (int w = 0; w < 4; ++w) { max_s[w][t] = ENC_NEG_INF; sum_s[w][t] = 0ull; }
    }
    __syncthreads();

    int gid = blockIdx.x * 256 + t;
    int nv  = n >> 2;

    float4 pr[ITERS];
    int4   bi[ITERS];
#pragma unroll
    for (int u = 0; u < ITERS; ++u) {
        int i = gid + u * (NB * 256);
        if (i < nv) {
            float4 cv = ((const float4*)coh)[i];
            int4   bv = ((const int4*)batch)[i];
            float4 pv;
            pv.x = cv.x * unc_s[bv.x];
            pv.y = cv.y * unc_s[bv.y];
            pv.z = cv.z * unc_s[bv.z];
            pv.w = cv.w * unc_s[bv.w];
            pr[u] = pv; bi[u] = bv;
            ((float4*)pri)[i] = pv;
            if (use8)
                ((uchar4*)b8)[i] = make_uchar4((unsigned char)bv.x, (unsigned char)bv.y,
                                               (unsigned char)bv.z, (unsigned char)bv.w);
            // conditional atomicMax: plain read first, RMW only on improvement
            unsigned e0 = enc_f32(pv.x); if (e0 > max_s[wv][bv.x]) atomicMax(&max_s[wv][bv.x], e0);
            unsigned e1 = enc_f32(pv.y); if (e1 > max_s[wv][bv.y]) atomicMax(&max_s[wv][bv.y], e1);
            unsigned e2 = enc_f32(pv.z); if (e2 > max_s[wv][bv.z]) atomicMax(&max_s[wv][bv.z], e2);
            unsigned e3 = enc_f32(pv.w); if (e3 > max_s[wv][bv.w]) atomicMax(&max_s[wv][bv.w], e3);
        } else {
            bi[u].x = -1;
        }
    }
    // scalar tail (n % 4), block 0 only
    float p_t = 0.0f; int b_t = -1;
    if (blockIdx.x == 0) {
        int rem = n - (nv << 2);
        if (t < rem) {
            int i = (nv << 2) + t;
            b_t = batch[i];
            p_t = coh[i] * unc_s[b_t];
            pri[i] = p_t;
            if (use8) b8[i] = (unsigned char)b_t;
            atomicMax(&max_s[wv][b_t], enc_f32(p_t));
        }
    }
    __syncthreads();
    if (t < BSEG) {
        unsigned m = max(max(max_s[0][t], max_s[1][t]), max(max_s[2][t], max_s[3][t]));
        float mf = dec_f32(m);
        m_s[t] = mf;
        bmax_t[t * NB + blockIdx.x] = mf;
    }
    __syncthreads();

    // replay from registers: partial sums exp(p - m_blk) in fixed-point u64
#pragma unroll
    for (int u = 0; u < ITERS; ++u) {
        if (bi[u].x >= 0) {
            int4 bv = bi[u]; float4 pv = pr[u];
            atomicAdd(&sum_s[wv][bv.x], (unsigned long long)(expf(pv.x - m_s[bv.x]) * SCALE_F));
            atomicAdd(&sum_s[wv][bv.y], (unsigned long long)(expf(pv.y - m_s[bv.y]) * SCALE_F));
            atomicAdd(&sum_s[wv][bv.z], (unsigned long long)(expf(pv.z - m_s[bv.z]) * SCALE_F));
            atomicAdd(&sum_s[wv][bv.w], (unsigned long long)(expf(pv.w - m_s[bv.w]) * SCALE_F));
        }
    }
    if (b_t >= 0)
        atomicAdd(&sum_s[wv][b_t], (unsigned long long)(expf(p_t - m_s[b_t]) * SCALE_F));
    __syncthreads();
    if (t < BSEG) {
        unsigned long long tot = sum_s[0][t] + sum_s[1][t] + sum_s[2][t] + sum_s[3][t];
        bsum_t[t * NB + blockIdx.x] = (float)((double)tot * INV_SCALE);
    }
}

// Combine: block s merges NB partials -> global max + reciprocal sum.
__global__ __launch_bounds__(256) void k_combine(const float* __restrict__ bmax_t,
                                                 const float* __restrict__ bsum_t,
                                                 float* __restrict__ maxf,
                                                 float* __restrict__ rsum) {
    int s = blockIdx.x, t = threadIdx.x;
    const float* bm = bmax_t + s * NB;
    const float* bs = bsum_t + s * NB;
    float m = -INFINITY;
    for (int i = t; i < NB; i += 256) m = fmaxf(m, bm[i]);
#pragma unroll
    for (int off = 32; off > 0; off >>= 1) m = fmaxf(m, __shfl_down(m, off, 64));
    __shared__ float part[4];
    if ((t & 63) == 0) part[t >> 6] = m;
    __syncthreads();
    float m_g = fmaxf(fmaxf(part[0], part[1]), fmaxf(part[2], part[3]));
    double acc = 0.0;
    for (int i = t; i < NB; i += 256) {
        float bmi = bm[i];
        acc += (double)bs[i] * (double)expf(bmi - m_g);
    }
#pragma unroll
    for (int off = 32; off > 0; off >>= 1) acc += __shfl_down(acc, off, 64);
    __shared__ double part2[4];
    if ((t & 63) == 0) part2[t >> 6] = acc;
    __syncthreads();
    if (t == 0) {
        double tot = part2[0] + part2[1] + part2[2] + part2[3];
        maxf[s] = m_g;
        rsum[s] = (float)(1.0 / tot);
    }
}

// Pass 2: normalized = exp(pri - maxf[b]) * rsum[b]
__global__ __launch_bounds__(256, 8) void k_pass2(
    const float* __restrict__ pri, const int* __restrict__ batch,
    const unsigned char* __restrict__ b8,
    const float* __restrict__ maxf, const float* __restrict__ rsum,
    float* __restrict__ nrm, int n, int use8) {
    __shared__ float m_s[BSEG];
    __shared__ float r_s[BSEG];
    int t = threadIdx.x;
    if (t < BSEG) { m_s[t] = maxf[t]; r_s[t] = rsum[t]; }
    __syncthreads();
    int gid = blockIdx.x * 256 + t;
    int gstride = NB2 * 256;
    int nv = n >> 2;
    if (use8) {
        for (int i = gid; i < nv; i += gstride) {
            float4 pv = ((const float4*)pri)[i];
            uchar4 bv = ((const uchar4*)b8)[i];
            float4 ov;
            ov.x = expf(pv.x - m_s[bv.x]) * r_s[bv.x];
            ov.y = expf(pv.y - m_s[bv.y]) * r_s[bv.y];
            ov.z = expf(pv.z - m_s[bv.z]) * r_s[bv.z];
            ov.w = expf(pv.w - m_s[bv.w]) * r_s[bv.w];
            ((float4*)nrm)[i] = ov;
        }
    } else {
        for (int i = gid; i < nv; i += gstride) {
            float4 pv = ((const float4*)pri)[i];
            int4   bv = ((const int4*)batch)[i];
            float4 ov;
            ov.x = expf(pv.x - m_s[bv.x]) * r_s[bv.x];
            ov.y = expf(pv.y - m_s[bv.y]) * r_s[bv.y];
            ov.z = expf(pv.z - m_s[bv.z]) * r_s[bv.z];
            ov.w = expf(pv.w - m_s[bv.w]) * r_s[bv.w];
            ((float4*)nrm)[i] = ov;
        }
    }
    for (int i = (nv << 2) + gid; i < n; i += gstride) {
        int b = batch[i];
        nrm[i] = expf(pri[i] - m_s[b]) * r_s[b];
    }
}

extern "C" void kernel_launch(void* const* d_in, const int* in_sizes, int n_in,
                              void* d_out, int out_size, void* d_ws, size_t ws_size,
                              hipStream_t stream) {
    const float* coh   = (const float*)d_in[0];
    // d_in[1] = posterior_mean (unused by the reference outputs)
    const float* pstd  = (const float*)d_in[2];
    const int*   batch = (const int*)d_in[3];
    int n = in_sizes[0];

    float* out     = (float*)d_out;
    float* out_pri = out;
    float* out_nrm = out + n;
    float* out_unc = out + 2 * (size_t)n;

    // ws layout (bytes):
    // [0,256)    unc
    // [256,512)  maxf
    // [512,768)  rsum
    // [1024, +NB*64*4)       bmax_t (transposed [seg][block])
    // [+NB*64*4, +2*NB*64*4) bsum_t
    // [base8, base8+n)       optional u8 batch sidecar
    size_t part_bytes = (size_t)NB * BSEG * 4;
    size_t base8      = 1024 + 2 * part_bytes;
    int    use8       = (ws_size >= base8 + (size_t)n) ? 1 : 0;

    float*         ws_unc  = (float*)d_ws;
    float*         ws_maxf = (float*)((char*)d_ws + 256);
    float*         ws_rsum = (float*)((char*)d_ws + 512);
    float*         ws_bmax = (float*)((char*)d_ws + 1024);
    float*         ws_bsum = (float*)((char*)d_ws + 1024 + part_bytes);
    unsigned char* ws_b8   = (unsigned char*)d_ws + base8;

    k_unc    <<<BSEG, 256, 0, stream>>>(pstd, ws_unc, out_unc);
    k_pass1  <<<NB,   256, 0, stream>>>(coh, batch, ws_unc, ws_bmax, ws_bsum,
                                        ws_b8, out_pri, n, use8);
    k_combine<<<BSEG, 256, 0, stream>>>(ws_bmax, ws_bsum, ws_maxf, ws_rsum);
    k_pass2  <<<NB2,  256, 0, stream>>>(out_pri, batch, ws_b8, ws_maxf, ws_rsum,
                                        out_nrm, n, use8);
}